// Round 5
// baseline (144.384 us; speedup 1.0000x reference)
//
#include <hip/hip_runtime.h>

// out[b,i,h,w] = w1 * x[b,0,h,w-s1] * (w>=s1) + w2 * x[b,0,h,w+s2] * (w+s2<256)
//   s1 = (i+1)>>1 in [0,128],  s2 = (i+2)>>1 in [1,128]
// x: (2,1,256,256) f32 (512 KB, cache-resident); out: (2,256,256,256) f32
// (128 MiB) -> pure write-BW bound (~21 us floor @ 6.5 TB/s).
//
// Single kernel, no LDS, no padding pass. Block = (b, h, 64-wide i-chunk);
// lane t = output column. s1/s2 are wave-uniform (SGPRs); taps are stride-1
// coalesced L1-hit loads with per-lane clamp + cndmask for the boundary.
// One coalesced nontemporal dword store per lane per i.

__global__ __launch_bounds__(256) void ConvolutionalOverlap_kernel(
    const float* __restrict__ x,
    const float* __restrict__ w1p,
    const float* __restrict__ w2p,
    float* __restrict__ out)
{
    const int t   = threadIdx.x;       // output column w, 0..255
    const int bid = blockIdx.x;        // 2048 = b(2) * h(256) * ichunk(4)
    const int b   = bid >> 10;
    const int h   = (bid >> 2) & 255;
    const int ic  = bid & 3;

    const float w1 = w1p[0];
    const float w2 = w2p[0];

    const float* __restrict__ row = x + (b << 16) + (h << 8);   // 1 KiB, L1-hot
    float* __restrict__ op = out + (b << 24) + (ic << 22) + (h << 8) + t;

    #pragma unroll 8
    for (int ii = 0; ii < 64; ++ii) {
        const int i  = (ic << 6) + ii;     // uniform -> SGPR
        const int s1 = (i + 1) >> 1;
        const int s2 = (i + 2) >> 1;

        const int a1 = t - s1;             // tap addresses, per-lane
        const int a2 = t + s2;

        float v1 = row[a1 < 0 ? 0 : a1];   // clamped coalesced L1 loads
        float v2 = row[a2 > 255 ? 255 : a2];
        v1 = (a1 < 0)   ? 0.0f : v1;       // boundary masks via cndmask
        v2 = (a2 > 255) ? 0.0f : v2;

        __builtin_nontemporal_store(w1 * v1 + w2 * v2, op);
        op += 1 << 16;                     // next i plane
    }
}

extern "C" void kernel_launch(void* const* d_in, const int* in_sizes, int n_in,
                              void* d_out, int out_size, void* d_ws, size_t ws_size,
                              hipStream_t stream) {
    const float* x  = (const float*)d_in[0];
    const float* w1 = (const float*)d_in[1];
    const float* w2 = (const float*)d_in[2];
    float* out = (float*)d_out;

    hipLaunchKernelGGL(ConvolutionalOverlap_kernel, dim3(2048), dim3(256), 0,
                       stream, x, w1, w2, out);
}